// Round 2
// baseline (1081.843 us; speedup 1.0000x reference)
//
#include <hip/hip_runtime.h>

typedef __attribute__((ext_vector_type(8))) short short8;
typedef __attribute__((ext_vector_type(4))) short short4v;
typedef __attribute__((ext_vector_type(4))) int   int4v;
typedef __attribute__((ext_vector_type(2))) int   int2v;
typedef __attribute__((ext_vector_type(4))) float float4v;
typedef __attribute__((ext_vector_type(2))) float float2v;

static __device__ __forceinline__ unsigned short f2bf(float f) {
  unsigned int u = __float_as_uint(f);
  return (unsigned short)((u + 0x8000u) >> 16);   // round-half-up (cheap)
}
// pack two f32 -> one dword of two bf16 (lo=a, hi=b): 2 adds + 1 v_perm
static __device__ __forceinline__ unsigned packbf2(float a, float b) {
  unsigned ua = __float_as_uint(a) + 0x8000u;
  unsigned ub = __float_as_uint(b) + 0x8000u;
  return __builtin_amdgcn_perm(ub, ua, 0x07060302);  // {ub[3],ub[2],ua[3],ua[2]}
}
static __device__ __forceinline__ float2v s2(float s) { return (float2v){s, s}; }
static __device__ __forceinline__ float2v fma2(float2v a, float2v b, float2v c) {
  return __builtin_elementwise_fma(a, b, c);
}
static __device__ __forceinline__ float2v sig2(float2v x) {
  x = __builtin_elementwise_min(__builtin_elementwise_max(x, s2(-2.4f)), s2(2.4f));
  float2v x2 = x * x;
  float2v t = fma2(x2, s2(0.0010218f), s2(-0.0191312f));
  t = fma2(t, x2, s2(0.25f));
  return fma2(x, t, s2(0.5f));
}
static __device__ __forceinline__ float2v tanh2(float2v x) {
  x = __builtin_elementwise_min(__builtin_elementwise_max(x, s2(-1.2f)), s2(1.2f));
  float2v x2 = x * x;
  float2v t = fma2(x2, s2(0.0654f), s2(-0.3061f));
  t = fma2(t, x2, s2(1.0f));
  return x * t;
}

#define MFMA16x16(a, b, c) __builtin_amdgcn_mfma_f32_16x16x32_bf16((a), (b), (c), 0, 0, 0)

// Gather a B-frag with the feature permutation phi(z) = 16*(z&3) + (z>>2) (+off).
// frag element j lives at column 16*(j&3) + 2q + (j>>2) + off of `row`.
static __device__ __forceinline__ short8 gather_frag_perm(const float* row, int q, int off) {
  float2v f0 = *(const float2v*)(row + 2 * q + off);
  float2v f1 = *(const float2v*)(row + 2 * q + off + 16);
  float2v f2 = *(const float2v*)(row + 2 * q + off + 32);
  float2v f3 = *(const float2v*)(row + 2 * q + off + 48);
  int4v pk = {(int)packbf2(f0.x, f1.x), (int)packbf2(f2.x, f3.x),
              (int)packbf2(f0.y, f1.y), (int)packbf2(f2.y, f3.y)};
  return __builtin_bit_cast(short8, pk);
}

// ======================= Kernel 1: GRU -> h_last (bf16) ======================
// 64 rows/block, 16 rows/wave. LDS 21504 B. 3 waves/SIMD target.
__global__ __launch_bounds__(256, 3) void gru_kernel(
    const float* __restrict__ cent,
    const float* __restrict__ Wih, const float* __restrict__ Whh,
    const float* __restrict__ bih, const float* __restrict__ bhh,
    unsigned short* __restrict__ hlast /* [B][64] bf16, phi-permuted cols */)
{
  __shared__ short h_stage[64][72];                       // 9216 B, phi-permuted
  __shared__ __align__(16) int whh1[12 * 64 * 4];         // 12288 B: k=32..63 B-frags

  const int tid = (int)threadIdx.x;
  const int lane = tid & 63;
  const int wv = tid >> 6;
  const int c = lane & 15;
  const int q = lane >> 4;
  const int r0 = wv * 16;
  const long rowblk = (long)blockIdx.x * 64;

  // stage the k=32..63 half of Whh B-frags (shared by all waves)
  for (int i = tid; i < 768; i += 256) {
    int nt = i >> 6, L = i & 63, cc = L & 15, qq = L >> 4;
    const float* wrow = Whh + (long)(nt * 16 + cc) * 64;
    short8 f = gather_frag_perm(wrow, qq, 8);
    *(int4v*)&whh1[i * 4] = __builtin_bit_cast(int4v, f);
  }
  // zero own h rows (h0 = 0); wave-private
  {
    int* hz = (int*)&h_stage[r0][0];
    for (int i = lane; i < 576; i += 64) hz[i] = 0;
  }
  __syncthreads();

  // k=0..31 half of Whh B-frags in registers
  short8 whhf0[12];
#pragma unroll
  for (int nt = 0; nt < 12; ++nt)
    whhf0[nt] = gather_frag_perm(Whh + (long)(nt * 16 + c) * 64, c >> 4 * 0 + q, 0);

  // per-lane GRU constants (gate index = t*16 + c, unpermuted)
  float accb_r[4], accb_z[4], accb_n[4], bxn[4];
  float wr0[4], wr1[4], wz0[4], wz1[4], wn0[4], wn1[4];
#pragma unroll
  for (int t = 0; t < 4; ++t) {
    int gr = t * 16 + c, gz = 64 + gr, gn = 128 + gr;
    accb_r[t] = bih[gr] + bhh[gr];
    accb_z[t] = bih[gz] + bhh[gz];
    accb_n[t] = bhh[gn];
    bxn[t] = bih[gn];
    wr0[t] = Wih[2 * gr]; wr1[t] = Wih[2 * gr + 1];
    wz0[t] = Wih[2 * gz]; wz1[t] = Wih[2 * gz + 1];
    wn0[t] = Wih[2 * gn]; wn1[t] = Wih[2 * gn + 1];
  }

  const float* cbase = cent + (rowblk + r0 + q * 4) * 32;
  float2v hp[4][2];
#pragma unroll
  for (int t = 0; t < 4; ++t) { hp[t][0] = s2(0.f); hp[t][1] = s2(0.f); }

  float x0[4], x1[4];
#pragma unroll
  for (int g = 0; g < 4; ++g) {
    float2v xv = *(const float2v*)(cbase + g * 32);
    x0[g] = xv.x; x1[g] = xv.y;
  }

  const float4v ZV = {0.f, 0.f, 0.f, 0.f};

  for (int s = 0; s < 16; ++s) {
    short8 a0 = *(const short8*)&h_stage[r0 + c][q * 8];
    short8 a1 = *(const short8*)&h_stage[r0 + c][32 + q * 8];
    float4v acc[12];
#pragma unroll
    for (int nt = 0; nt < 12; ++nt) {
      short8 b1 = *(const short8*)&whh1[(nt * 64 + lane) * 4];
      acc[nt] = MFMA16x16(a0, whhf0[nt], ZV);
      acc[nt] = MFMA16x16(a1, b1, acc[nt]);
    }
    float nx0[4], nx1[4];
    if (s < 15) {
#pragma unroll
      for (int g = 0; g < 4; ++g) {
        float2v xv = *(const float2v*)(cbase + g * 32 + (s + 1) * 2);
        nx0[g] = xv.x; nx1[g] = xv.y;
      }
    }
    float2v x0p[2] = {{x0[0], x0[1]}, {x0[2], x0[3]}};
    float2v x1p[2] = {{x1[0], x1[1]}, {x1[2], x1[3]}};
#pragma unroll
    for (int t = 0; t < 4; ++t) {
#pragma unroll
      for (int gp = 0; gp < 2; ++gp) {
        float2v hr = {acc[t][2 * gp], acc[t][2 * gp + 1]};
        float2v hz = {acc[t + 4][2 * gp], acc[t + 4][2 * gp + 1]};
        float2v hn = {acc[t + 8][2 * gp], acc[t + 8][2 * gp + 1]};
        float2v r = sig2(fma2(s2(wr0[t]), x0p[gp], fma2(s2(wr1[t]), x1p[gp], hr + accb_r[t])));
        float2v z = sig2(fma2(s2(wz0[t]), x0p[gp], fma2(s2(wz1[t]), x1p[gp], hz + accb_z[t])));
        float2v xn = fma2(s2(wn0[t]), x0p[gp], fma2(s2(wn1[t]), x1p[gp], s2(bxn[t])));
        float2v n = tanh2(fma2(r, hn + accb_n[t], xn));
        float2v h = fma2(z, hp[t][gp] - n, n);
        hp[t][gp] = h;
      }
    }
    // pack & store: position z = 4c + t (phi-permuted) -> b64, conflict-free
#pragma unroll
    for (int gp = 0; gp < 2; ++gp)
#pragma unroll
      for (int i = 0; i < 2; ++i) {
        int g = gp * 2 + i;
        int2v pk = {(int)packbf2(hp[0][gp][i], hp[1][gp][i]),
                    (int)packbf2(hp[2][gp][i], hp[3][gp][i])};
        *(int2v*)&h_stage[r0 + q * 4 + g][4 * c] = pk;
      }
    if (s < 15) {
#pragma unroll
      for (int g = 0; g < 4; ++g) { x0[g] = nx0[g]; x1[g] = nx1[g]; }
    }
  }

  // coalesced b128 write-out of h_last (raw permuted layout)
  {
    int rr = lane >> 2, pp = lane & 3;
    int4v hv = *(const int4v*)&h_stage[r0 + rr][pp * 16];
    *(int4v*)&hlast[(rowblk + r0 + rr) * 64 + pp * 16] = hv;
  }
}

// ============== Kernel 2: traj-proj + appear-proj + fuse + GELU ==============
// LDS 54272 B -> 3 blocks/CU. fusedA is wave-private (rows r0..r0+15).
__global__ __launch_bounds__(256, 3) void tail_kernel(
    const float* __restrict__ emb, const unsigned short* __restrict__ hlast,
    const float* __restrict__ Wt, const float* __restrict__ bt,
    const float* __restrict__ Wa, const float* __restrict__ ba,
    const float* __restrict__ Wf, const float* __restrict__ bfv,
    float* __restrict__ out)
{
  __shared__ short fusedA[64][264];   // 33792 B: [appear | traj] bf16
  __shared__ short wbuf[10240];       // 20480 B: Wa dbuf 2x[128][40] / Wf [128][72]

  const int tid = (int)threadIdx.x;
  const int lane = tid & 63;
  const int wv = tid >> 6;
  const int c = lane & 15;
  const int q = lane >> 4;
  const int r0 = wv * 16;
  const long rowblk = (long)blockIdx.x * 64;

  // ---- traj proj: h_last (phi-permuted bf16) @ Wt'^T + bt ----
  {
    short8 a0 = *(const short8*)&hlast[(rowblk + r0 + c) * 64 + q * 8];
    short8 a1 = *(const short8*)&hlast[(rowblk + r0 + c) * 64 + 32 + q * 8];
#pragma unroll
    for (int nt = 0; nt < 8; ++nt) {
      int col = nt * 16 + c;
      const float* wrow = Wt + (long)col * 64;
      short8 b0 = gather_frag_perm(wrow, q, 0);
      short8 b1 = gather_frag_perm(wrow, q, 8);
      float bv = bt[col];
      float4v acc = {bv, bv, bv, bv};
      acc = MFMA16x16(a0, b0, acc);
      acc = MFMA16x16(a1, b1, acc);
#pragma unroll
      for (int g = 0; g < 4; ++g)
        fusedA[r0 + q * 4 + g][128 + col] = (short)f2bf(acc[g]);
    }
  }

  // ---- appearance proj: stream emb, Wa chunks double-buffered in LDS ----
  {
    short (*wa0)[40] = (short(*)[40])(&wbuf[0]);
    short (*wa1)[40] = (short(*)[40])(&wbuf[5120]);
    float4v accA[8];
#pragma unroll
    for (int nt = 0; nt < 8; ++nt) {
      float bv = ba[nt * 16 + c];
      accA[nt] = (float4v){bv, bv, bv, bv};
    }
    const float* erow = emb + (rowblk + r0 + c) * 512;
    float4v e0 = *(const float4v*)(erow + q * 8);
    float4v e1 = *(const float4v*)(erow + q * 8 + 4);
    for (int kc = 0; kc < 16; ++kc) {
      short (*buf)[40] = (kc & 1) ? wa1 : wa0;
#pragma unroll
      for (int j = 0; j < 4; ++j) {
        int f4 = tid + j * 256;
        int n = f4 >> 3, c4 = f4 & 7;
        float4v v = *(const float4v*)(Wa + (long)n * 512 + kc * 32 + c4 * 4);
        int2v pk = {(int)packbf2(v.x, v.y), (int)packbf2(v.z, v.w)};
        *(int2v*)&buf[n][c4 * 4] = pk;
      }
      float4v p0 = e0, p1 = e1;
      if (kc < 15) {
        p0 = *(const float4v*)(erow + (kc + 1) * 32 + q * 8);
        p1 = *(const float4v*)(erow + (kc + 1) * 32 + q * 8 + 4);
      }
      __syncthreads();
      int4v epk = {(int)packbf2(e0.x, e0.y), (int)packbf2(e0.z, e0.w),
                   (int)packbf2(e1.x, e1.y), (int)packbf2(e1.z, e1.w)};
      short8 ea = __builtin_bit_cast(short8, epk);
#pragma unroll
      for (int nt = 0; nt < 8; ++nt) {
        short8 wb = *(const short8*)&buf[nt * 16 + c][q * 8];
        accA[nt] = MFMA16x16(ea, wb, accA[nt]);
      }
      e0 = p0; e1 = p1;
    }
#pragma unroll
    for (int nt = 0; nt < 8; ++nt)
#pragma unroll
      for (int g = 0; g < 4; ++g)
        fusedA[r0 + q * 4 + g][nt * 16 + c] = (short)f2bf(accA[nt][g]);
  }

  // ---- fuse: [appear|traj] @ Wf^T + bf, exact GELU ----
  {
    short (*wfs)[72] = (short(*)[72])wbuf;
    float4v accF[8];
#pragma unroll
    for (int nt = 0; nt < 8; ++nt) {
      float bv = bfv[nt * 16 + c];
      accF[nt] = (float4v){bv, bv, bv, bv};
    }
    for (int kc = 0; kc < 4; ++kc) {
      __syncthreads();
#pragma unroll
      for (int j = 0; j < 8; ++j) {
        int f4 = tid + j * 256;
        int n = f4 >> 4, c4 = f4 & 15;
        float4v v = *(const float4v*)(Wf + (long)n * 256 + kc * 64 + c4 * 4);
        int2v pk = {(int)packbf2(v.x, v.y), (int)packbf2(v.z, v.w)};
        *(int2v*)&wfs[n][c4 * 4] = pk;
      }
      __syncthreads();
#pragma unroll
      for (int ki = 0; ki < 2; ++ki) {
        short8 fa = *(const short8*)&fusedA[r0 + c][kc * 64 + ki * 32 + q * 8];
#pragma unroll
        for (int nt = 0; nt < 8; ++nt) {
          short8 wb = *(const short8*)&wfs[nt * 16 + c][ki * 32 + q * 8];
          accF[nt] = MFMA16x16(fa, wb, accF[nt]);
        }
      }
    }
    float* orow = out + (rowblk + r0 + q * 4) * 128;
#pragma unroll
    for (int nt = 0; nt < 8; ++nt) {
#pragma unroll
      for (int g = 0; g < 4; ++g) {
        float xv = accF[nt][g];
        float gl = 0.5f * xv * (1.0f + erff(xv * 0.70710678f));
        orow[(long)g * 128 + nt * 16 + c] = gl;
      }
    }
  }
}

// ===================== Fallback: round-1 fused kernel ========================
static __device__ __forceinline__ short8 pack8f(float4v a, float4v b) {
  int4v pk = {(int)packbf2(a.x, a.y), (int)packbf2(a.z, a.w),
              (int)packbf2(b.x, b.y), (int)packbf2(b.z, b.w)};
  return __builtin_bit_cast(short8, pk);
}
static __device__ __forceinline__ float sig_poly(float x) {
  x = fminf(2.4f, fmaxf(-2.4f, x));
  float x2 = x * x;
  float t = fmaf(0.0010218f, x2, -0.0191312f);
  t = fmaf(t, x2, 0.25f);
  return fmaf(x, t, 0.5f);
}
static __device__ __forceinline__ float tanh_poly(float x) {
  x = fminf(1.2f, fmaxf(-1.2f, x));
  float x2 = x * x;
  float t = fmaf(0.0654f, x2, -0.3061f);
  t = fmaf(t, x2, 1.0f);
  return x * t;
}
__global__ __launch_bounds__(256, 2) void tie_kernel(
    const float* __restrict__ emb, const float* __restrict__ cent,
    const float* __restrict__ Wih, const float* __restrict__ Whh,
    const float* __restrict__ bih, const float* __restrict__ bhh,
    const float* __restrict__ Wt, const float* __restrict__ bt,
    const float* __restrict__ Wa, const float* __restrict__ ba,
    const float* __restrict__ Wf, const float* __restrict__ bfv,
    float* __restrict__ out)
{
  __shared__ short fused_in[64][264];
  __shared__ short h_stage[64][72];
  __shared__ short wscratch[10240];
  const int tid = (int)threadIdx.x;
  const int lane = tid & 63;
  const int wv = tid >> 6;
  const int c = lane & 15;
  const int q = lane >> 4;
  const int r0 = wv * 16;
  const long rowblk = (long)blockIdx.x * 64;
  {
    short4v z = {0, 0, 0, 0};
    short4v* hp2 = (short4v*)&h_stage[r0][0];
    for (int i = lane; i < 288; i += 64) hp2[i] = z;
  }
  float accb_r[4], accb_z[4], accb_n[4], bxn[4];
  float wr0[4], wr1[4], wz0[4], wz1[4], wn0[4], wn1[4];
#pragma unroll
  for (int t = 0; t < 4; ++t) {
    int gr = t * 16 + c, gz = 64 + t * 16 + c, gn = 128 + t * 16 + c;
    accb_r[t] = bih[gr] + bhh[gr];
    accb_z[t] = bih[gz] + bhh[gz];
    accb_n[t] = bhh[gn];
    bxn[t] = bih[gn];
    wr0[t] = Wih[2 * gr]; wr1[t] = Wih[2 * gr + 1];
    wz0[t] = Wih[2 * gz]; wz1[t] = Wih[2 * gz + 1];
    wn0[t] = Wih[2 * gn]; wn1[t] = Wih[2 * gn + 1];
  }
  short8 whhf[12][2];
#pragma unroll
  for (int nt = 0; nt < 12; ++nt) {
    const float* wp = Whh + (long)(nt * 16 + c) * 64 + q * 8;
    whhf[nt][0] = pack8f(*(const float4v*)(wp), *(const float4v*)(wp + 4));
    whhf[nt][1] = pack8f(*(const float4v*)(wp + 32), *(const float4v*)(wp + 36));
  }
  const float* cbase = cent + (rowblk + r0 + q * 4) * 32;
  float hprev[4][4];
#pragma unroll
  for (int t = 0; t < 4; ++t)
#pragma unroll
    for (int g = 0; g < 4; ++g) hprev[t][g] = 0.0f;
  float x0[4], x1[4];
#pragma unroll
  for (int g = 0; g < 4; ++g) {
    float2 xv = *(const float2*)(cbase + g * 32);
    x0[g] = xv.x; x1[g] = xv.y;
  }
  for (int s = 0; s < 16; ++s) {
    short8 a0 = *(const short8*)&h_stage[r0 + c][q * 8];
    short8 a1 = *(const short8*)&h_stage[r0 + c][32 + q * 8];
    float4v acc[12];
#pragma unroll
    for (int t = 0; t < 4; ++t) {
      acc[t]     = (float4v){accb_r[t], accb_r[t], accb_r[t], accb_r[t]};
      acc[t + 4] = (float4v){accb_z[t], accb_z[t], accb_z[t], accb_z[t]};
      acc[t + 8] = (float4v){accb_n[t], accb_n[t], accb_n[t], accb_n[t]};
    }
#pragma unroll
    for (int nt = 0; nt < 12; ++nt) {
      acc[nt] = MFMA16x16(a0, whhf[nt][0], acc[nt]);
      acc[nt] = MFMA16x16(a1, whhf[nt][1], acc[nt]);
    }
    float nx0[4], nx1[4];
    if (s < 15) {
#pragma unroll
      for (int g = 0; g < 4; ++g) {
        float2 xv = *(const float2*)(cbase + g * 32 + (s + 1) * 2);
        nx0[g] = xv.x; nx1[g] = xv.y;
      }
    }
#pragma unroll
    for (int t = 0; t < 4; ++t) {
#pragma unroll
      for (int g = 0; g < 4; ++g) {
        float hr = acc[t][g], hz = acc[t + 4][g], hn = acc[t + 8][g];
        float r = sig_poly(fmaf(wr0[t], x0[g], fmaf(wr1[t], x1[g], hr)));
        float z = sig_poly(fmaf(wz0[t], x0[g], fmaf(wz1[t], x1[g], hz)));
        float xn = fmaf(wn0[t], x0[g], fmaf(wn1[t], x1[g], bxn[t]));
        float n = tanh_poly(fmaf(r, hn, xn));
        float h = fmaf(z, hprev[t][g] - n, n);
        hprev[t][g] = h;
        h_stage[r0 + q * 4 + g][t * 16 + c] = (short)f2bf(h);
      }
    }
    if (s < 15) {
#pragma unroll
      for (int g = 0; g < 4; ++g) { x0[g] = nx0[g]; x1[g] = nx1[g]; }
    }
  }
  {
    short8 a0 = *(const short8*)&h_stage[r0 + c][q * 8];
    short8 a1 = *(const short8*)&h_stage[r0 + c][32 + q * 8];
#pragma unroll
    for (int nt = 0; nt < 8; ++nt) {
      int col = nt * 16 + c;
      const float* wp = Wt + (long)col * 64 + q * 8;
      short8 b0 = pack8f(*(const float4v*)(wp), *(const float4v*)(wp + 4));
      short8 b1 = pack8f(*(const float4v*)(wp + 32), *(const float4v*)(wp + 36));
      float bv = bt[col];
      float4v acc = (float4v){bv, bv, bv, bv};
      acc = MFMA16x16(a0, b0, acc);
      acc = MFMA16x16(a1, b1, acc);
#pragma unroll
      for (int g = 0; g < 4; ++g)
        fused_in[r0 + q * 4 + g][128 + col] = (short)f2bf(acc[g]);
    }
  }
  {
    short (*wa0)[40] = (short(*)[40])(&wscratch[0]);
    short (*wa1)[40] = (short(*)[40])(&wscratch[5120]);
    float4v accA[8];
#pragma unroll
    for (int nt = 0; nt < 8; ++nt) {
      float bv = ba[nt * 16 + c];
      accA[nt] = (float4v){bv, bv, bv, bv};
    }
    const float* erow = emb + (rowblk + r0 + c) * 512;
    float4v e0 = *(const float4v*)(erow + q * 8);
    float4v e1 = *(const float4v*)(erow + q * 8 + 4);
    for (int kc = 0; kc < 16; ++kc) {
      short (*buf)[40] = (kc & 1) ? wa1 : wa0;
#pragma unroll
      for (int j = 0; j < 4; ++j) {
        int f4 = tid + j * 256;
        int n = f4 >> 3, c4 = f4 & 7;
        float4v v = *(const float4v*)(Wa + (long)n * 512 + kc * 32 + c4 * 4);
        int2v pk = {(int)packbf2(v.x, v.y), (int)packbf2(v.z, v.w)};
        *(int2v*)&buf[n][c4 * 4] = pk;
      }
      float4v p0 = e0, p1 = e1;
      if (kc < 15) {
        p0 = *(const float4v*)(erow + (kc + 1) * 32 + q * 8);
        p1 = *(const float4v*)(erow + (kc + 1) * 32 + q * 8 + 4);
      }
      __syncthreads();
      short8 ea = pack8f(e0, e1);
#pragma unroll
      for (int nt = 0; nt < 8; ++nt) {
        short8 wb = *(const short8*)&buf[nt * 16 + c][q * 8];
        accA[nt] = MFMA16x16(ea, wb, accA[nt]);
      }
      e0 = p0; e1 = p1;
    }
#pragma unroll
    for (int nt = 0; nt < 8; ++nt)
#pragma unroll
      for (int g = 0; g < 4; ++g)
        fused_in[r0 + q * 4 + g][nt * 16 + c] = (short)f2bf(accA[nt][g]);
  }
  __syncthreads();
  {
    short (*wf_s)[72] = (short(*)[72])wscratch;
    float4v accF[8];
#pragma unroll
    for (int nt = 0; nt < 8; ++nt) {
      float bv = bfv[nt * 16 + c];
      accF[nt] = (float4v){bv, bv, bv, bv};
    }
    for (int kc = 0; kc < 4; ++kc) {
      if (kc) __syncthreads();
#pragma unroll
      for (int j = 0; j < 8; ++j) {
        int f4 = tid + j * 256;
        int n = f4 >> 4, c4 = f4 & 15;
        float4v v = *(const float4v*)(Wf + (long)n * 256 + kc * 64 + c4 * 4);
        int2v pk = {(int)packbf2(v.x, v.y), (int)packbf2(v.z, v.w)};
        *(int2v*)&wf_s[n][c4 * 4] = pk;
      }
      __syncthreads();
#pragma unroll
      for (int ki = 0; ki < 2; ++ki) {
        short8 fa = *(const short8*)&fused_in[r0 + c][kc * 64 + ki * 32 + q * 8];
#pragma unroll
        for (int nt = 0; nt < 8; ++nt) {
          short8 wb = *(const short8*)&wf_s[nt * 16 + c][ki * 32 + q * 8];
          accF[nt] = MFMA16x16(fa, wb, accF[nt]);
        }
      }
    }
    float* orow = out + (rowblk + r0 + q * 4) * 128;
#pragma unroll
  for (int nt = 0; nt < 8; ++nt) {
#pragma unroll
      for (int g = 0; g < 4; ++g) {
        float xv = accF[nt][g];
        float gl = 0.5f * xv * (1.0f + erff(xv * 0.70710678f));
        orow[(long)g * 128 + nt * 16 + c] = gl;
      }
    }
  }
}

extern "C" void kernel_launch(void* const* d_in, const int* in_sizes, int n_in,
                              void* d_out, int out_size, void* d_ws, size_t ws_size,
                              hipStream_t stream) {
  const float* emb = (const float*)d_in[0];
  const float* cent = (const float*)d_in[1];
  const float* Wih = (const float*)d_in[2];
  const float* Whh = (const float*)d_in[3];
  const float* bih = (const float*)d_in[4];
  const float* bhh = (const float*)d_in[5];
  const float* Wt  = (const float*)d_in[6];
  const float* bt  = (const float*)d_in[7];
  const float* Wa  = (const float*)d_in[8];
  const float* ba  = (const float*)d_in[9];
  const float* Wf  = (const float*)d_in[10];
  const float* bfv = (const float*)d_in[11];
  float* out = (float*)d_out;

  const int B = in_sizes[0] / 512;
  dim3 grid(B / 64), block(256);

  if (ws_size >= (size_t)B * 64 * sizeof(unsigned short)) {
    unsigned short* hlast = (unsigned short*)d_ws;
    hipLaunchKernelGGL(gru_kernel, grid, block, 0, stream,
                       cent, Wih, Whh, bih, bhh, hlast);
    hipLaunchKernelGGL(tail_kernel, grid, block, 0, stream,
                       emb, hlast, Wt, bt, Wa, ba, Wf, bfv, out);
  } else {
    hipLaunchKernelGGL(tie_kernel, grid, block, 0, stream,
                       emb, cent, Wih, Whh, bih, bhh, Wt, bt, Wa, ba, Wf, bfv, out);
  }
}

// Round 3
// 1074.408 us; speedup vs baseline: 1.0069x; 1.0069x over previous
//
#include <hip/hip_runtime.h>

typedef __attribute__((ext_vector_type(8))) short short8;
typedef __attribute__((ext_vector_type(4))) short short4v;
typedef __attribute__((ext_vector_type(4))) int   int4v;
typedef __attribute__((ext_vector_type(2))) int   int2v;
typedef __attribute__((ext_vector_type(4))) float float4v;
typedef __attribute__((ext_vector_type(2))) float float2v;

static __device__ __forceinline__ unsigned short f2bf(float f) {
  unsigned int u = __float_as_uint(f);
  return (unsigned short)((u + 0x8000u) >> 16);   // round-half-up (cheap)
}
// pack two f32 -> one dword of two bf16 (lo=a, hi=b): 2 adds + 1 v_perm
static __device__ __forceinline__ unsigned packbf2(float a, float b) {
  unsigned ua = __float_as_uint(a) + 0x8000u;
  unsigned ub = __float_as_uint(b) + 0x8000u;
  return __builtin_amdgcn_perm(ub, ua, 0x07060302);  // {ub[3],ub[2],ua[3],ua[2]}
}
static __device__ __forceinline__ float2v s2(float s) { return (float2v){s, s}; }
static __device__ __forceinline__ float2v fma2(float2v a, float2v b, float2v c) {
  return __builtin_elementwise_fma(a, b, c);
}
static __device__ __forceinline__ float2v sig2(float2v x) {
  x = __builtin_elementwise_min(__builtin_elementwise_max(x, s2(-2.4f)), s2(2.4f));
  float2v x2 = x * x;
  float2v t = fma2(x2, s2(0.0010218f), s2(-0.0191312f));
  t = fma2(t, x2, s2(0.25f));
  return fma2(x, t, s2(0.5f));
}
static __device__ __forceinline__ float2v tanh2(float2v x) {
  x = __builtin_elementwise_min(__builtin_elementwise_max(x, s2(-1.2f)), s2(1.2f));
  float2v x2 = x * x;
  float2v t = fma2(x2, s2(0.0654f), s2(-0.3061f));
  t = fma2(t, x2, s2(1.0f));
  return x * t;
}

#define MFMA16x16(a, b, c) __builtin_amdgcn_mfma_f32_16x16x32_bf16((a), (b), (c), 0, 0, 0)

// Gather a B-frag with the feature permutation phi(p) = 16*(p&3) + (p>>2) (+off).
// frag element j (k = off_k + q*8 + j) lives at column 16*(j&3) + 2q + (j>>2) + off.
static __device__ __forceinline__ short8 gather_frag_perm(const float* row, int q, int off) {
  float2v f0 = *(const float2v*)(row + 2 * q + off);
  float2v f1 = *(const float2v*)(row + 2 * q + off + 16);
  float2v f2 = *(const float2v*)(row + 2 * q + off + 32);
  float2v f3 = *(const float2v*)(row + 2 * q + off + 48);
  int4v pk = {(int)packbf2(f0.x, f1.x), (int)packbf2(f2.x, f3.x),
              (int)packbf2(f0.y, f1.y), (int)packbf2(f2.y, f3.y)};
  return __builtin_bit_cast(short8, pk);
}

// ======================= Kernel 1: GRU -> h_last (bf16) ======================
// 64 rows/block, 16 rows/wave. LDS 33792 B -> 3 blocks/CU with (256,3).
// All Whh B-frags live in LDS: register demand ~130 < 168 cap -> no spill.
__global__ __launch_bounds__(256, 3) void gru_kernel(
    const float* __restrict__ cent,
    const float* __restrict__ Wih, const float* __restrict__ Whh,
    const float* __restrict__ bih, const float* __restrict__ bhh,
    unsigned short* __restrict__ hlast /* [B][64] bf16, phi-permuted cols */)
{
  __shared__ short h_stage[64][72];                 // 9216 B, phi-permuted
  __shared__ __align__(16) int whhB[24 * 64 * 4];   // 24576 B: all B-frags

  const int tid = (int)threadIdx.x;
  const int lane = tid & 63;
  const int wv = tid >> 6;
  const int c = lane & 15;
  const int q = lane >> 4;
  const int r0 = wv * 16;
  const long rowblk = (long)blockIdx.x * 64;

  // stage all 24 Whh B-frags (frag f = nt*2+kf; entry (f,L) at whhB[(f*64+L)*4])
  for (int i = tid; i < 1536; i += 256) {
    int f = i >> 6, L = i & 63;
    int cc = L & 15, qq = L >> 4;
    int nt = f >> 1, kf = f & 1;
    short8 fr = gather_frag_perm(Whh + (long)(nt * 16 + cc) * 64, qq, kf * 8);
    *(int4v*)&whhB[i * 4] = __builtin_bit_cast(int4v, fr);
  }
  // zero own h rows (h0 = 0); wave-private region
  {
    int* hz = (int*)&h_stage[r0][0];
    for (int i = lane; i < 576; i += 64) hz[i] = 0;
  }

  // per-lane GRU constants (gate/output col = t*16 + c)
  float accb_r[4], accb_z[4], accb_n[4], bxn[4];
  float wr0[4], wr1[4], wz0[4], wz1[4], wn0[4], wn1[4];
#pragma unroll
  for (int t = 0; t < 4; ++t) {
    int gr = t * 16 + c, gz = 64 + gr, gn = 128 + gr;
    accb_r[t] = bih[gr] + bhh[gr];
    accb_z[t] = bih[gz] + bhh[gz];
    accb_n[t] = bhh[gn];          // n-gate: r multiplies (hn + b_hh) only
    bxn[t] = bih[gn];
    wr0[t] = Wih[2 * gr]; wr1[t] = Wih[2 * gr + 1];
    wz0[t] = Wih[2 * gz]; wz1[t] = Wih[2 * gz + 1];
    wn0[t] = Wih[2 * gn]; wn1[t] = Wih[2 * gn + 1];
  }
  __syncthreads();

  const float* cbase = cent + (rowblk + r0 + q * 4) * 32;
  float2v hp[4][2];
#pragma unroll
  for (int t = 0; t < 4; ++t) { hp[t][0] = s2(0.f); hp[t][1] = s2(0.f); }

  const float4v ZV = {0.f, 0.f, 0.f, 0.f};

#pragma unroll 1
  for (int s = 0; s < 16; ++s) {
    short8 a0 = *(const short8*)&h_stage[r0 + c][q * 8];
    short8 a1 = *(const short8*)&h_stage[r0 + c][32 + q * 8];
    float4v acc[12];
#pragma unroll
    for (int nt = 0; nt < 12; ++nt) {
      short8 b0 = *(const short8*)&whhB[(nt * 2 + 0) * 256 + lane * 4];
      short8 b1 = *(const short8*)&whhB[(nt * 2 + 1) * 256 + lane * 4];
      acc[nt] = MFMA16x16(a0, b0, ZV);
      acc[nt] = MFMA16x16(a1, b1, acc[nt]);
    }
    // x for this step (L1-resident after s=0: rows re-touched 16x)
    float2v x0p[2], x1p[2];
#pragma unroll
    for (int gp = 0; gp < 2; ++gp) {
      float2v xa = *(const float2v*)(cbase + (2 * gp) * 32 + s * 2);
      float2v xb = *(const float2v*)(cbase + (2 * gp + 1) * 32 + s * 2);
      x0p[gp] = (float2v){xa.x, xb.x};
      x1p[gp] = (float2v){xa.y, xb.y};
    }
#pragma unroll
    for (int t = 0; t < 4; ++t) {
#pragma unroll
      for (int gp = 0; gp < 2; ++gp) {
        float2v hr = {acc[t][2 * gp], acc[t][2 * gp + 1]};
        float2v hz = {acc[t + 4][2 * gp], acc[t + 4][2 * gp + 1]};
        float2v hn = {acc[t + 8][2 * gp], acc[t + 8][2 * gp + 1]};
        float2v r = sig2(fma2(s2(wr0[t]), x0p[gp], fma2(s2(wr1[t]), x1p[gp], hr + accb_r[t])));
        float2v z = sig2(fma2(s2(wz0[t]), x0p[gp], fma2(s2(wz1[t]), x1p[gp], hz + accb_z[t])));
        float2v xn = fma2(s2(wn0[t]), x0p[gp], fma2(s2(wn1[t]), x1p[gp], s2(bxn[t])));
        float2v n = tanh2(fma2(r, hn + accb_n[t], xn));
        float2v h = fma2(z, hp[t][gp] - n, n);
        hp[t][gp] = h;
      }
    }
    // pack & store: LDS position p = 4c + t (phi-permuted) -> b64, conflict-free
#pragma unroll
    for (int gp = 0; gp < 2; ++gp)
#pragma unroll
      for (int i = 0; i < 2; ++i) {
        int g = gp * 2 + i;
        int2v pk = {(int)packbf2(hp[0][gp][i], hp[1][gp][i]),
                    (int)packbf2(hp[2][gp][i], hp[3][gp][i])};
        *(int2v*)&h_stage[r0 + q * 4 + g][4 * c] = pk;
      }
  }

  // coalesced b128 write-out of h_last (raw permuted layout)
  {
    int rr = lane >> 2, pp = lane & 3;
    int4v hv = *(const int4v*)&h_stage[r0 + rr][pp * 16];
    *(int4v*)&hlast[(rowblk + r0 + rr) * 64 + pp * 16] = hv;
  }
}

// ============== Kernel 2: traj-proj + appear-proj + fuse + GELU ==============
// LDS 54272 B. (256,2): 256-reg budget -> spill-proof (round-1-proven regime).
__global__ __launch_bounds__(256, 2) void tail_kernel(
    const float* __restrict__ emb, const unsigned short* __restrict__ hlast,
    const float* __restrict__ Wt, const float* __restrict__ bt,
    const float* __restrict__ Wa, const float* __restrict__ ba,
    const float* __restrict__ Wf, const float* __restrict__ bfv,
    float* __restrict__ out)
{
  __shared__ short fusedA[64][264];   // 33792 B: [appear | traj] bf16
  __shared__ short wbuf[10240];       // 20480 B: Wa dbuf 2x[128][40] / Wf [128][72]

  const int tid = (int)threadIdx.x;
  const int lane = tid & 63;
  const int wv = tid >> 6;
  const int c = lane & 15;
  const int q = lane >> 4;
  const int r0 = wv * 16;
  const long rowblk = (long)blockIdx.x * 64;

  // ---- traj proj: h_last (phi-permuted bf16) @ Wt'^T + bt ----
  {
    short8 a0 = *(const short8*)&hlast[(rowblk + r0 + c) * 64 + q * 8];
    short8 a1 = *(const short8*)&hlast[(rowblk + r0 + c) * 64 + 32 + q * 8];
#pragma unroll
    for (int nt = 0; nt < 8; ++nt) {
      int col = nt * 16 + c;
      const float* wrow = Wt + (long)col * 64;
      short8 b0 = gather_frag_perm(wrow, q, 0);
      short8 b1 = gather_frag_perm(wrow, q, 8);
      float bv = bt[col];
      float4v acc = {bv, bv, bv, bv};
      acc = MFMA16x16(a0, b0, acc);
      acc = MFMA16x16(a1, b1, acc);
#pragma unroll
      for (int g = 0; g < 4; ++g)
        fusedA[r0 + q * 4 + g][128 + col] = (short)f2bf(acc[g]);
    }
  }

  // ---- appearance proj: stream emb, Wa chunks double-buffered in LDS ----
  {
    short (*wa0)[40] = (short(*)[40])(&wbuf[0]);
    short (*wa1)[40] = (short(*)[40])(&wbuf[5120]);
    float4v accA[8];
#pragma unroll
    for (int nt = 0; nt < 8; ++nt) {
      float bv = ba[nt * 16 + c];
      accA[nt] = (float4v){bv, bv, bv, bv};
    }
    const float* erow = emb + (rowblk + r0 + c) * 512;
    float4v e0 = *(const float4v*)(erow + q * 8);
    float4v e1 = *(const float4v*)(erow + q * 8 + 4);
    for (int kc = 0; kc < 16; ++kc) {
      short (*buf)[40] = (kc & 1) ? wa1 : wa0;
#pragma unroll
      for (int j = 0; j < 4; ++j) {
        int f4 = tid + j * 256;
        int n = f4 >> 3, c4 = f4 & 7;
        float4v v = *(const float4v*)(Wa + (long)n * 512 + kc * 32 + c4 * 4);
        int2v pk = {(int)packbf2(v.x, v.y), (int)packbf2(v.z, v.w)};
        *(int2v*)&buf[n][c4 * 4] = pk;
      }
      float4v p0 = e0, p1 = e1;
      if (kc < 15) {
        p0 = *(const float4v*)(erow + (kc + 1) * 32 + q * 8);
        p1 = *(const float4v*)(erow + (kc + 1) * 32 + q * 8 + 4);
      }
      __syncthreads();
      int4v epk = {(int)packbf2(e0.x, e0.y), (int)packbf2(e0.z, e0.w),
                   (int)packbf2(e1.x, e1.y), (int)packbf2(e1.z, e1.w)};
      short8 ea = __builtin_bit_cast(short8, epk);
#pragma unroll
      for (int nt = 0; nt < 8; ++nt) {
        short8 wb = *(const short8*)&buf[nt * 16 + c][q * 8];
        accA[nt] = MFMA16x16(ea, wb, accA[nt]);
      }
      e0 = p0; e1 = p1;
    }
#pragma unroll
    for (int nt = 0; nt < 8; ++nt)
#pragma unroll
      for (int g = 0; g < 4; ++g)
        fusedA[r0 + q * 4 + g][nt * 16 + c] = (short)f2bf(accA[nt][g]);
  }

  // ---- fuse: [appear|traj] @ Wf^T + bf, exact GELU ----
  {
    short (*wfs)[72] = (short(*)[72])wbuf;
    float4v accF[8];
#pragma unroll
    for (int nt = 0; nt < 8; ++nt) {
      float bv = bfv[nt * 16 + c];
      accF[nt] = (float4v){bv, bv, bv, bv};
    }
    for (int kc = 0; kc < 4; ++kc) {
      __syncthreads();
#pragma unroll
      for (int j = 0; j < 8; ++j) {
        int f4 = tid + j * 256;
        int n = f4 >> 4, c4 = f4 & 15;
        float4v v = *(const float4v*)(Wf + (long)n * 256 + kc * 64 + c4 * 4);
        int2v pk = {(int)packbf2(v.x, v.y), (int)packbf2(v.z, v.w)};
        *(int2v*)&wfs[n][c4 * 4] = pk;
      }
      __syncthreads();
#pragma unroll
      for (int ki = 0; ki < 2; ++ki) {
        short8 fa = *(const short8*)&fusedA[r0 + c][kc * 64 + ki * 32 + q * 8];
#pragma unroll
        for (int nt = 0; nt < 8; ++nt) {
          short8 wb = *(const short8*)&wfs[nt * 16 + c][ki * 32 + q * 8];
          accF[nt] = MFMA16x16(fa, wb, accF[nt]);
        }
      }
    }
    float* orow = out + (rowblk + r0 + q * 4) * 128;
#pragma unroll
    for (int nt = 0; nt < 8; ++nt) {
#pragma unroll
      for (int g = 0; g < 4; ++g) {
        float xv = accF[nt][g];
        float gl = 0.5f * xv * (1.0f + erff(xv * 0.70710678f));
        orow[(long)g * 128 + nt * 16 + c] = gl;
      }
    }
  }
}

// ===================== Fallback: round-1-style fused kernel ==================
static __device__ __forceinline__ short8 pack8f(float4v a, float4v b) {
  int4v pk = {(int)packbf2(a.x, a.y), (int)packbf2(a.z, a.w),
              (int)packbf2(b.x, b.y), (int)packbf2(b.z, b.w)};
  return __builtin_bit_cast(short8, pk);
}
static __device__ __forceinline__ float sig_poly(float x) {
  x = fminf(2.4f, fmaxf(-2.4f, x));
  float x2 = x * x;
  float t = fmaf(0.0010218f, x2, -0.0191312f);
  t = fmaf(t, x2, 0.25f);
  return fmaf(x, t, 0.5f);
}
static __device__ __forceinline__ float tanh_poly(float x) {
  x = fminf(1.2f, fmaxf(-1.2f, x));
  float x2 = x * x;
  float t = fmaf(0.0654f, x2, -0.3061f);
  t = fmaf(t, x2, 1.0f);
  return x * t;
}
__global__ __launch_bounds__(256, 2) void tie_kernel(
    const float* __restrict__ emb, const float* __restrict__ cent,
    const float* __restrict__ Wih, const float* __restrict__ Whh,
    const float* __restrict__ bih, const float* __restrict__ bhh,
    const float* __restrict__ Wt, const float* __restrict__ bt,
    const float* __restrict__ Wa, const float* __restrict__ ba,
    const float* __restrict__ Wf, const float* __restrict__ bfv,
    float* __restrict__ out)
{
  __shared__ short fused_in[64][264];
  __shared__ short h_stage[64][72];
  __shared__ short wscratch[10240];
  const int tid = (int)threadIdx.x;
  const int lane = tid & 63;
  const int wv = tid >> 6;
  const int c = lane & 15;
  const int q = lane >> 4;
  const int r0 = wv * 16;
  const long rowblk = (long)blockIdx.x * 64;
  {
    short4v z = {0, 0, 0, 0};
    short4v* hp2 = (short4v*)&h_stage[r0][0];
    for (int i = lane; i < 288; i += 64) hp2[i] = z;
  }
  float accb_r[4], accb_z[4], accb_n[4], bxn[4];
  float wr0[4], wr1[4], wz0[4], wz1[4], wn0[4], wn1[4];
#pragma unroll
  for (int t = 0; t < 4; ++t) {
    int gr = t * 16 + c, gz = 64 + t * 16 + c, gn = 128 + t * 16 + c;
    accb_r[t] = bih[gr] + bhh[gr];
    accb_z[t] = bih[gz] + bhh[gz];
    accb_n[t] = bhh[gn];
    bxn[t] = bih[gn];
    wr0[t] = Wih[2 * gr]; wr1[t] = Wih[2 * gr + 1];
    wz0[t] = Wih[2 * gz]; wz1[t] = Wih[2 * gz + 1];
    wn0[t] = Wih[2 * gn]; wn1[t] = Wih[2 * gn + 1];
  }
  short8 whhf[12][2];
#pragma unroll
  for (int nt = 0; nt < 12; ++nt) {
    const float* wp = Whh + (long)(nt * 16 + c) * 64 + q * 8;
    whhf[nt][0] = pack8f(*(const float4v*)(wp), *(const float4v*)(wp + 4));
    whhf[nt][1] = pack8f(*(const float4v*)(wp + 32), *(const float4v*)(wp + 36));
  }
  const float* cbase = cent + (rowblk + r0 + q * 4) * 32;
  float hprev[4][4];
#pragma unroll
  for (int t = 0; t < 4; ++t)
#pragma unroll
    for (int g = 0; g < 4; ++g) hprev[t][g] = 0.0f;
  float x0[4], x1[4];
#pragma unroll
  for (int g = 0; g < 4; ++g) {
    float2 xv = *(const float2*)(cbase + g * 32);
    x0[g] = xv.x; x1[g] = xv.y;
  }
  for (int s = 0; s < 16; ++s) {
    short8 a0 = *(const short8*)&h_stage[r0 + c][q * 8];
    short8 a1 = *(const short8*)&h_stage[r0 + c][32 + q * 8];
    float4v acc[12];
#pragma unroll
    for (int t = 0; t < 4; ++t) {
      acc[t]     = (float4v){accb_r[t], accb_r[t], accb_r[t], accb_r[t]};
      acc[t + 4] = (float4v){accb_z[t], accb_z[t], accb_z[t], accb_z[t]};
      acc[t + 8] = (float4v){accb_n[t], accb_n[t], accb_n[t], accb_n[t]};
    }
#pragma unroll
    for (int nt = 0; nt < 12; ++nt) {
      acc[nt] = MFMA16x16(a0, whhf[nt][0], acc[nt]);
      acc[nt] = MFMA16x16(a1, whhf[nt][1], acc[nt]);
    }
    float nx0[4], nx1[4];
    if (s < 15) {
#pragma unroll
      for (int g = 0; g < 4; ++g) {
        float2 xv = *(const float2*)(cbase + g * 32 + (s + 1) * 2);
        nx0[g] = xv.x; nx1[g] = xv.y;
      }
    }
#pragma unroll
    for (int t = 0; t < 4; ++t) {
#pragma unroll
      for (int g = 0; g < 4; ++g) {
        float hr = acc[t][g], hz = acc[t + 4][g], hn = acc[t + 8][g];
        float r = sig_poly(fmaf(wr0[t], x0[g], fmaf(wr1[t], x1[g], hr)));
        float z = sig_poly(fmaf(wz0[t], x0[g], fmaf(wz1[t], x1[g], hz)));
        float xn = fmaf(wn0[t], x0[g], fmaf(wn1[t], x1[g], bxn[t]));
        float n = tanh_poly(fmaf(r, hn, xn));
        float h = fmaf(z, hprev[t][g] - n, n);
        hprev[t][g] = h;
        h_stage[r0 + q * 4 + g][t * 16 + c] = (short)f2bf(h);
      }
    }
    if (s < 15) {
#pragma unroll
      for (int g = 0; g < 4; ++g) { x0[g] = nx0[g]; x1[g] = nx1[g]; }
    }
  }
  {
    short8 a0 = *(const short8*)&h_stage[r0 + c][q * 8];
    short8 a1 = *(const short8*)&h_stage[r0 + c][32 + q * 8];
#pragma unroll
    for (int nt = 0; nt < 8; ++nt) {
      int col = nt * 16 + c;
      const float* wp = Wt + (long)col * 64 + q * 8;
      short8 b0 = pack8f(*(const float4v*)(wp), *(const float4v*)(wp + 4));
      short8 b1 = pack8f(*(const float4v*)(wp + 32), *(const float4v*)(wp + 36));
      float bv = bt[col];
      float4v acc = (float4v){bv, bv, bv, bv};
      acc = MFMA16x16(a0, b0, acc);
      acc = MFMA16x16(a1, b1, acc);
#pragma unroll
      for (int g = 0; g < 4; ++g)
        fused_in[r0 + q * 4 + g][128 + col] = (short)f2bf(acc[g]);
    }
  }
  {
    short (*wa0)[40] = (short(*)[40])(&wscratch[0]);
    short (*wa1)[40] = (short(*)[40])(&wscratch[5120]);
    float4v accA[8];
#pragma unroll
    for (int nt = 0; nt < 8; ++nt) {
      float bv = ba[nt * 16 + c];
      accA[nt] = (float4v){bv, bv, bv, bv};
    }
    const float* erow = emb + (rowblk + r0 + c) * 512;
    float4v e0 = *(const float4v*)(erow + q * 8);
    float4v e1 = *(const float4v*)(erow + q * 8 + 4);
    for (int kc = 0; kc < 16; ++kc) {
      short (*buf)[40] = (kc & 1) ? wa1 : wa0;
#pragma unroll
      for (int j = 0; j < 4; ++j) {
        int f4 = tid + j * 256;
        int n = f4 >> 3, c4 = f4 & 7;
        float4v v = *(const float4v*)(Wa + (long)n * 512 + kc * 32 + c4 * 4);
        int2v pk = {(int)packbf2(v.x, v.y), (int)packbf2(v.z, v.w)};
        *(int2v*)&buf[n][c4 * 4] = pk;
      }
      float4v p0 = e0, p1 = e1;
      if (kc < 15) {
        p0 = *(const float4v*)(erow + (kc + 1) * 32 + q * 8);
        p1 = *(const float4v*)(erow + (kc + 1) * 32 + q * 8 + 4);
      }
      __syncthreads();
      short8 ea = pack8f(e0, e1);
#pragma unroll
      for (int nt = 0; nt < 8; ++nt) {
        short8 wb = *(const short8*)&buf[nt * 16 + c][q * 8];
        accA[nt] = MFMA16x16(ea, wb, accA[nt]);
      }
      e0 = p0; e1 = p1;
    }
#pragma unroll
    for (int nt = 0; nt < 8; ++nt)
#pragma unroll
      for (int g = 0; g < 4; ++g)
        fused_in[r0 + q * 4 + g][nt * 16 + c] = (short)f2bf(accA[nt][g]);
  }
  __syncthreads();
  {
    short (*wf_s)[72] = (short(*)[72])wscratch;
    float4v accF[8];
#pragma unroll
    for (int nt = 0; nt < 8; ++nt) {
      float bv = bfv[nt * 16 + c];
      accF[nt] = (float4v){bv, bv, bv, bv};
    }
    for (int kc = 0; kc < 4; ++kc) {
      if (kc) __syncthreads();
#pragma unroll
      for (int j = 0; j < 8; ++j) {
        int f4 = tid + j * 256;
        int n = f4 >> 4, c4 = f4 & 15;
        float4v v = *(const float4v*)(Wf + (long)n * 256 + kc * 64 + c4 * 4);
        int2v pk = {(int)packbf2(v.x, v.y), (int)packbf2(v.z, v.w)};
        *(int2v*)&wf_s[n][c4 * 4] = pk;
      }
      __syncthreads();
#pragma unroll
      for (int ki = 0; ki < 2; ++ki) {
        short8 fa = *(const short8*)&fused_in[r0 + c][kc * 64 + ki * 32 + q * 8];
#pragma unroll
        for (int nt = 0; nt < 8; ++nt) {
          short8 wb = *(const short8*)&wf_s[nt * 16 + c][ki * 32 + q * 8];
          accF[nt] = MFMA16x16(fa, wb, accF[nt]);
        }
      }
    }
    float* orow = out + (rowblk + r0 + q * 4) * 128;
#pragma unroll
    for (int nt = 0; nt < 8; ++nt) {
#pragma unroll
      for (int g = 0; g < 4; ++g) {
        float xv = accF[nt][g];
        float gl = 0.5f * xv * (1.0f + erff(xv * 0.70710678f));
        orow[(long)g * 128 + nt * 16 + c] = gl;
      }
    }
  }
}

extern "C" void kernel_launch(void* const* d_in, const int* in_sizes, int n_in,
                              void* d_out, int out_size, void* d_ws, size_t ws_size,
                              hipStream_t stream) {
  const float* emb = (const float*)d_in[0];
  const float* cent = (const float*)d_in[1];
  const float* Wih = (const float*)d_in[2];
  const float* Whh = (const float*)d_in[3];
  const float* bih = (const float*)d_in[4];
  const float* bhh = (const float*)d_in[5];
  const float* Wt  = (const float*)d_in[6];
  const float* bt  = (const float*)d_in[7];
  const float* Wa  = (const float*)d_in[8];
  const float* ba  = (const float*)d_in[9];
  const float* Wf  = (const float*)d_in[10];
  const float* bfv = (const float*)d_in[11];
  float* out = (float*)d_out;

  const int B = in_sizes[0] / 512;
  dim3 grid(B / 64), block(256);

  if (ws_size >= (size_t)B * 64 * sizeof(unsigned short)) {
    unsigned short* hlast = (unsigned short*)d_ws;
    hipLaunchKernelGGL(gru_kernel, grid, block, 0, stream,
                       cent, Wih, Whh, bih, bhh, hlast);
    hipLaunchKernelGGL(tail_kernel, grid, block, 0, stream,
                       emb, hlast, Wt, bt, Wa, ba, Wf, bfv, out);
  } else {
    hipLaunchKernelGGL(tie_kernel, grid, block, 0, stream,
                       emb, cent, Wih, Whh, bih, bhh, Wt, bt, Wa, ba, Wf, bfv, out);
  }
}

// Round 4
// 861.690 us; speedup vs baseline: 1.2555x; 1.2469x over previous
//
#include <hip/hip_runtime.h>

typedef __attribute__((ext_vector_type(8))) short short8;
typedef __attribute__((ext_vector_type(4))) int   int4v;
typedef __attribute__((ext_vector_type(2))) int   int2v;
typedef __attribute__((ext_vector_type(4))) float float4v;
typedef __attribute__((ext_vector_type(2))) float float2v;

static __device__ __forceinline__ unsigned short f2bf(float f) {
  unsigned int u = __float_as_uint(f);
  return (unsigned short)((u + 0x8000u) >> 16);
}
// pack two f32 -> dword of two bf16 (lo=a, hi=b): 2 adds + 1 v_perm
static __device__ __forceinline__ unsigned packbf2(float a, float b) {
  unsigned ua = __float_as_uint(a) + 0x8000u;
  unsigned ub = __float_as_uint(b) + 0x8000u;
  return __builtin_amdgcn_perm(ub, ua, 0x07060302);
}
static __device__ __forceinline__ short8 pack8f(float4v a, float4v b) {
  int4v pk = {(int)packbf2(a.x, a.y), (int)packbf2(a.z, a.w),
              (int)packbf2(b.x, b.y), (int)packbf2(b.z, b.w)};
  return __builtin_bit_cast(short8, pk);
}
static __device__ __forceinline__ float2v s2(float s) { return (float2v){s, s}; }
static __device__ __forceinline__ float2v fma2(float2v a, float2v b, float2v c) {
  return __builtin_elementwise_fma(a, b, c);
}
static __device__ __forceinline__ float2v sig2(float2v x) {
  x = __builtin_elementwise_min(__builtin_elementwise_max(x, s2(-2.4f)), s2(2.4f));
  float2v x2 = x * x;
  float2v t = fma2(x2, s2(0.0010218f), s2(-0.0191312f));
  t = fma2(t, x2, s2(0.25f));
  return fma2(x, t, s2(0.5f));
}
static __device__ __forceinline__ float2v tanh2(float2v x) {
  x = __builtin_elementwise_min(__builtin_elementwise_max(x, s2(-1.2f)), s2(1.2f));
  float2v x2 = x * x;
  float2v t = fma2(x2, s2(0.0654f), s2(-0.3061f));
  t = fma2(t, x2, s2(1.0f));
  return x * t;
}

#define MFMA16x16(a, b, c) __builtin_amdgcn_mfma_f32_16x16x32_bf16((a), (b), (c), 0, 0, 0)

// B-frag gather under the feature permutation z(p)=16*(p&3)+(p>>2):
// frag element j (k-pos p = kf*32 + q*8 + j) reads row[off + 2q + 16*(j&3) + (j>>2)],
// call with off = group_base + kf*8.
static __device__ __forceinline__ short8 gather_frag_perm(const float* row, int q, int off) {
  float2v f0 = *(const float2v*)(row + 2 * q + off);
  float2v f1 = *(const float2v*)(row + 2 * q + off + 16);
  float2v f2 = *(const float2v*)(row + 2 * q + off + 32);
  float2v f3 = *(const float2v*)(row + 2 * q + off + 48);
  int4v pk = {(int)packbf2(f0.x, f1.x), (int)packbf2(f2.x, f3.x),
              (int)packbf2(f0.y, f1.y), (int)packbf2(f2.y, f3.y)};
  return __builtin_bit_cast(short8, pk);
}

// Fused kernel: 64 rows/block, 16 rows/wave, 4 waves.
// LDS 50176 B (time-sliced unions) -> 3 blocks/CU if regs <= 168.
// (256,2): spill-proof register budget (the (256,3) variants scratch-spilled 1.8 GB).
__global__ __launch_bounds__(256, 2) void tie2_kernel(
    const float* __restrict__ emb, const float* __restrict__ cent,
    const float* __restrict__ Wih, const float* __restrict__ Whh,
    const float* __restrict__ bih, const float* __restrict__ bhh,
    const float* __restrict__ Wt, const float* __restrict__ bt,
    const float* __restrict__ Wa, const float* __restrict__ ba,
    const float* __restrict__ Wf, const float* __restrict__ bfv,
    float* __restrict__ out)
{
  // Region A: fusedA [64][264] bf16 (33792 B)  UNION  whhB 12 frags (12288 B, GRU phase)
  // Region B: h_stage [64][72] bf16 (9216 B)   UNION  Wa frag dbuf 2x8192 B (appear phase)
  __shared__ __align__(16) char lds_a[64 * 264 * 2];
  __shared__ __align__(16) char lds_b[16384];

  short (*fusedA)[264] = (short(*)[264])lds_a;
  int* whhB = (int*)lds_a;                     // [12 frags][64 lanes][4 dwords]
  short (*h_stage)[72] = (short(*)[72])lds_b;  // phi-permuted h

  const int tid = (int)threadIdx.x;
  const int lane = tid & 63;
  const int wv = tid >> 6;
  const int c = lane & 15;           // MFMA col / A-row index
  const int q = lane >> 4;           // MFMA quad
  const int r0 = wv * 16;
  const long rowblk = (long)blockIdx.x * 64;

  // ---- stage k=32..63 Whh B-frags into whhB (cooperative) ----
  for (int i = tid; i < 768; i += 256) {
    int nt = i >> 6, L = i & 63;
    int cc = L & 15, qq = L >> 4;
    short8 fr = gather_frag_perm(Whh + (long)(nt * 16 + cc) * 64, qq, 8); // kf=1
    *(int4v*)&whhB[i * 4] = __builtin_bit_cast(int4v, fr);
  }
  // zero own h rows (wave-private)
  {
    int* hz = (int*)&h_stage[r0][0];
    for (int i = lane; i < 576; i += 64) hz[i] = 0;
  }
  // k=0..31 Whh B-frags in registers (48 VGPR)
  short8 whhf0[12];
#pragma unroll
  for (int nt = 0; nt < 12; ++nt)
    whhf0[nt] = gather_frag_perm(Whh + (long)(nt * 16 + c) * 64, q, 0);  // kf=0

  // per-lane GRU constants (gate col = t*16 + c)
  float accb_r[4], accb_z[4], accb_n[4], bxn[4];
  float wr0[4], wr1[4], wz0[4], wz1[4], wn0[4], wn1[4];
#pragma unroll
  for (int t = 0; t < 4; ++t) {
    int gr = t * 16 + c, gz = 64 + gr, gn = 128 + gr;
    accb_r[t] = bih[gr] + bhh[gr];
    accb_z[t] = bih[gz] + bhh[gz];
    accb_n[t] = bhh[gn];             // n-gate: r multiplies (hn + b_hh) only
    bxn[t] = bih[gn];
    wr0[t] = Wih[2 * gr]; wr1[t] = Wih[2 * gr + 1];
    wz0[t] = Wih[2 * gz]; wz1[t] = Wih[2 * gz + 1];
    wn0[t] = Wih[2 * gn]; wn1[t] = Wih[2 * gn + 1];
  }
  __syncthreads();   // whhB staged

  // ---- GRU: 16 steps, barrier-free (wave-private h rows) ----
  const float* cbase = cent + (rowblk + r0 + q * 4) * 32;
  float2v hp[4][2];
#pragma unroll
  for (int t = 0; t < 4; ++t) { hp[t][0] = s2(0.f); hp[t][1] = s2(0.f); }
  const float4v ZV = {0.f, 0.f, 0.f, 0.f};

#pragma unroll 1
  for (int s = 0; s < 16; ++s) {
    short8 a0 = *(const short8*)&h_stage[r0 + c][q * 8];
    short8 a1 = *(const short8*)&h_stage[r0 + c][32 + q * 8];
    float4v acc[12];
#pragma unroll
    for (int nt = 0; nt < 12; ++nt) {
      short8 b1 = *(const short8*)&whhB[(nt * 64 + lane) * 4];
      acc[nt] = MFMA16x16(a0, whhf0[nt], ZV);
      acc[nt] = MFMA16x16(a1, b1, acc[nt]);
    }
    float2v x0p[2], x1p[2];
#pragma unroll
    for (int gp = 0; gp < 2; ++gp) {
      float2v xa = *(const float2v*)(cbase + (2 * gp) * 32 + s * 2);
      float2v xb = *(const float2v*)(cbase + (2 * gp + 1) * 32 + s * 2);
      x0p[gp] = (float2v){xa.x, xb.x};
      x1p[gp] = (float2v){xa.y, xb.y};
    }
#pragma unroll
    for (int t = 0; t < 4; ++t) {
#pragma unroll
      for (int gp = 0; gp < 2; ++gp) {
        float2v hr = {acc[t][2 * gp], acc[t][2 * gp + 1]};
        float2v hz = {acc[t + 4][2 * gp], acc[t + 4][2 * gp + 1]};
        float2v hn = {acc[t + 8][2 * gp], acc[t + 8][2 * gp + 1]};
        float2v r = sig2(fma2(s2(wr0[t]), x0p[gp], fma2(s2(wr1[t]), x1p[gp], hr + accb_r[t])));
        float2v z = sig2(fma2(s2(wz0[t]), x0p[gp], fma2(s2(wz1[t]), x1p[gp], hz + accb_z[t])));
        float2v xn = fma2(s2(wn0[t]), x0p[gp], fma2(s2(wn1[t]), x1p[gp], s2(bxn[t])));
        float2v n = tanh2(fma2(r, hn + accb_n[t], xn));
        float2v h = fma2(z, hp[t][gp] - n, n);
        hp[t][gp] = h;
      }
    }
    // phi-permuted b64 h-store (bank floor, conflict-free)
#pragma unroll
    for (int gp = 0; gp < 2; ++gp)
#pragma unroll
      for (int i = 0; i < 2; ++i) {
        int g = gp * 2 + i;
        int2v pk = {(int)packbf2(hp[0][gp][i], hp[1][gp][i]),
                    (int)packbf2(hp[2][gp][i], hp[3][gp][i])};
        *(int2v*)&h_stage[r0 + q * 4 + g][4 * c] = pk;
      }
  }

  __syncthreads();   // all waves done reading whhB; fusedA region now writable

  // ---- traj proj: h @ Wt^T + bt -> fusedA groups 2,3 (phi-permuted) ----
  {
    short8 a0 = *(const short8*)&h_stage[r0 + c][q * 8];
    short8 a1 = *(const short8*)&h_stage[r0 + c][32 + q * 8];
    float4v accT[8];
#pragma unroll
    for (int nt = 0; nt < 8; ++nt) {
      int col = nt * 16 + c;
      const float* wrow = Wt + (long)col * 64;
      short8 b0 = gather_frag_perm(wrow, q, 0);
      short8 b1 = gather_frag_perm(wrow, q, 8);
      float bv = bt[col];
      float4v acc = {bv, bv, bv, bv};
      acc = MFMA16x16(a0, b0, acc);
      accT[nt] = MFMA16x16(a1, b1, acc);
    }
#pragma unroll
    for (int g = 0; g < 4; ++g) {
      int row = r0 + q * 4 + g;
      int2v p2 = {(int)packbf2(accT[0][g], accT[1][g]), (int)packbf2(accT[2][g], accT[3][g])};
      int2v p3 = {(int)packbf2(accT[4][g], accT[5][g]), (int)packbf2(accT[6][g], accT[7][g])};
      *(int2v*)&fusedA[row][128 + 4 * c] = p2;   // group 2
      *(int2v*)&fusedA[row][192 + 4 * c] = p3;   // group 3
    }
  }
  __syncthreads();   // h_stage reads done; region B now Wa frag dbuf

  // ---- appearance proj: stream emb; Wa staged as pre-gathered frags (dbuf) ----
  {
    float4v accA[8];
#pragma unroll
    for (int nt = 0; nt < 8; ++nt) {
      float bv = ba[nt * 16 + c];
      accA[nt] = (float4v){bv, bv, bv, bv};
    }
    const float* erow = emb + (rowblk + r0 + c) * 512;
    float4v e0 = *(const float4v*)(erow + q * 8);
    float4v e1 = *(const float4v*)(erow + q * 8 + 4);
#pragma unroll 1
    for (int kc = 0; kc < 16; ++kc) {
      int* wab = (int*)(lds_b + (kc & 1) * 8192);
#pragma unroll
      for (int j = 0; j < 2; ++j) {          // stage 8 frags of Wa[:, kc*32:+32]
        int i = tid + j * 256;
        int nt = i >> 6, L = i & 63;
        int cc = L & 15, qq = L >> 4;
        const float* wp = Wa + (long)(nt * 16 + cc) * 512 + kc * 32 + qq * 8;
        short8 fr = pack8f(*(const float4v*)wp, *(const float4v*)(wp + 4));
        *(int4v*)&wab[i * 4] = __builtin_bit_cast(int4v, fr);
      }
      float4v p0 = e0, p1 = e1;
      if (kc < 15) {
        p0 = *(const float4v*)(erow + (kc + 1) * 32 + q * 8);
        p1 = *(const float4v*)(erow + (kc + 1) * 32 + q * 8 + 4);
      }
      __syncthreads();
      short8 ea = pack8f(e0, e1);
#pragma unroll
      for (int nt = 0; nt < 8; ++nt) {
        short8 wb = *(const short8*)&wab[(nt * 64 + lane) * 4];
        accA[nt] = MFMA16x16(ea, wb, accA[nt]);
      }
      e0 = p0; e1 = p1;
    }
#pragma unroll
    for (int g = 0; g < 4; ++g) {
      int row = r0 + q * 4 + g;
      int2v p0v = {(int)packbf2(accA[0][g], accA[1][g]), (int)packbf2(accA[2][g], accA[3][g])};
      int2v p1v = {(int)packbf2(accA[4][g], accA[5][g]), (int)packbf2(accA[6][g], accA[7][g])};
      *(int2v*)&fusedA[row][0 + 4 * c] = p0v;    // group 0
      *(int2v*)&fusedA[row][64 + 4 * c] = p1v;   // group 1
    }
  }

  // ---- fuse: fusedA @ Wf^T + bf, exact GELU. No barrier: A rows wave-private,
  //      B-frags gathered directly from L2 with matching phi permutation. ----
  {
    short8 fa[8];
#pragma unroll
    for (int gk = 0; gk < 8; ++gk)   // gk = grp*2 + kf
      fa[gk] = *(const short8*)&fusedA[r0 + c][gk * 32 + q * 8];
#pragma unroll
    for (int nt = 0; nt < 8; ++nt) {
      int col = nt * 16 + c;
      const float* wrow = Wf + (long)col * 256;
      float bv = bfv[col];
      float4v accF = {bv, bv, bv, bv};
#pragma unroll
      for (int gk = 0; gk < 8; ++gk) {
        short8 wb = gather_frag_perm(wrow + (gk >> 1) * 64, q, (gk & 1) * 8);
        accF = MFMA16x16(fa[gk], wb, accF);
      }
      float* orow = out + (rowblk + r0 + q * 4) * 128;
#pragma unroll
      for (int g = 0; g < 4; ++g) {
        float xv = accF[g];
        float gl = 0.5f * xv * (1.0f + erff(xv * 0.70710678f));
        orow[(long)g * 128 + col] = gl;
      }
    }
  }
}

extern "C" void kernel_launch(void* const* d_in, const int* in_sizes, int n_in,
                              void* d_out, int out_size, void* d_ws, size_t ws_size,
                              hipStream_t stream) {
  const float* emb = (const float*)d_in[0];
  const float* cent = (const float*)d_in[1];
  const float* Wih = (const float*)d_in[2];
  const float* Whh = (const float*)d_in[3];
  const float* bih = (const float*)d_in[4];
  const float* bhh = (const float*)d_in[5];
  const float* Wt  = (const float*)d_in[6];
  const float* bt  = (const float*)d_in[7];
  const float* Wa  = (const float*)d_in[8];
  const float* ba  = (const float*)d_in[9];
  const float* Wf  = (const float*)d_in[10];
  const float* bfv = (const float*)d_in[11];
  float* out = (float*)d_out;

  const int B = in_sizes[0] / 512;   // 131072
  dim3 grid(B / 64), block(256);
  hipLaunchKernelGGL(tie2_kernel, grid, block, 0, stream,
                     emb, cent, Wih, Whh, bih, bhh, Wt, bt, Wa, ba, Wf, bfv, out);
}